// Round 7
// baseline (238.405 us; speedup 1.0000x reference)
//
#include <hip/hip_runtime.h>

#define N_NODES 50000
#define N_EDGES 800000
#define IN_DIM 128
#define HID 64
#define NT 64        // nodes per block in gin layer
#define RST_PITCH 68 // 272B rows: 16B-aligned, conflict-free broadcasts
#define NXCD 8
#define NODES_PER_RANGE (N_NODES / NXCD)   // 6250
#define NBLK_N 196                         // ceil(N_NODES/256)

using v4f = __attribute__((ext_vector_type(4))) float;
using v4i = __attribute__((ext_vector_type(4))) int;

// ---------------- init: zero deg + zero row n of hA/hB ----------------
__global__ __launch_bounds__(256) void zero_kernel(int* __restrict__ deg,
                                                   float* __restrict__ hA,
                                                   float* __restrict__ hB) {
    int i = blockIdx.x * 256 + threadIdx.x;
    if (i < N_NODES) deg[i] = 0;
    if (blockIdx.x == 0 && threadIdx.x < HID) {
        hA[(size_t)N_NODES * HID + threadIdx.x] = 0.f;
        hB[(size_t)N_NODES * HID + threadIdx.x] = 0.f;
    }
}

// ---------------- CSR build ----------------
// XCD-affine dst-range sweep (range = blockIdx.x & 7; blockIdx->XCD is
// round-robin %8 on MI355X — perf heuristic only). Edge streams are read
// NON-TEMPORALLY so they don't evict the per-XCD col segment (~400KB) and
// cursor (25KB) from the 4MB L2: that thrash was the 30MB write-amp.

__global__ __launch_bounds__(256) void deg_sweep_kernel(
        const int* __restrict__ dst, int* __restrict__ deg) {
    int r = blockIdx.x & (NXCD - 1);
    int lo = r * NODES_PER_RANGE, hi = lo + NODES_PER_RANGE;
    int nch = gridDim.x >> 3;
    int cb = blockIdx.x >> 3;
    int stride = nch * blockDim.x;
    for (int t = cb * blockDim.x + threadIdx.x; t < N_EDGES / 4; t += stride) {
        v4i d4 = __builtin_nontemporal_load(reinterpret_cast<const v4i*>(dst) + t);
        if (d4.x >= lo && d4.x < hi) atomicAdd(&deg[d4.x], 1);
        if (d4.y >= lo && d4.y < hi) atomicAdd(&deg[d4.y], 1);
        if (d4.z >= lo && d4.z < hi) atomicAdd(&deg[d4.z], 1);
        if (d4.w >= lo && d4.w < hi) atomicAdd(&deg[d4.w], 1);
    }
}

__global__ __launch_bounds__(256) void fill_sweep_kernel(
        const int* __restrict__ src, const int* __restrict__ dst,
        int* __restrict__ cursor, int* __restrict__ col) {
    int r = blockIdx.x & (NXCD - 1);
    int lo = r * NODES_PER_RANGE, hi = lo + NODES_PER_RANGE;
    int nch = gridDim.x >> 3;
    int cb = blockIdx.x >> 3;
    int stride = nch * blockDim.x;
    for (int t = cb * blockDim.x + threadIdx.x; t < N_EDGES / 4; t += stride) {
        v4i d4 = __builtin_nontemporal_load(reinterpret_cast<const v4i*>(dst) + t);
        v4i s4 = __builtin_nontemporal_load(reinterpret_cast<const v4i*>(src) + t);
        if (d4.x >= lo && d4.x < hi) col[atomicAdd(&cursor[d4.x], 1)] = s4.x;
        if (d4.y >= lo && d4.y < hi) col[atomicAdd(&cursor[d4.y], 1)] = s4.y;
        if (d4.z >= lo && d4.z < hi) col[atomicAdd(&cursor[d4.z], 1)] = s4.z;
        if (d4.w >= lo && d4.w < hi) col[atomicAdd(&cursor[d4.w], 1)] = s4.w;
    }
}

__global__ void scan1_kernel(const int* __restrict__ deg, int* __restrict__ row_ptr,
                             int* __restrict__ blksum, int n) {
    __shared__ int sh[256];
    int t = threadIdx.x;
    int i = blockIdx.x * 256 + t;
    int v = (i < n) ? deg[i] : 0;
    sh[t] = v;
    __syncthreads();
    for (int off = 1; off < 256; off <<= 1) {
        int add = (t >= off) ? sh[t - off] : 0;
        __syncthreads();
        sh[t] += add;
        __syncthreads();
    }
    int incl = sh[t];
    if (i < n) row_ptr[i] = incl - v;
    if (t == 255) blksum[blockIdx.x] = incl;
}

// merged scan2+scan3: every block redundantly scans the 196 block sums in
// LDS (exclusive), then applies its own block offset to its row_ptr chunk.
__global__ void scan23_kernel(int* __restrict__ row_ptr, const int* __restrict__ blksum,
                              int* __restrict__ cursor, int n, int nE) {
    __shared__ int sh[256];
    int t = threadIdx.x;
    int v = (t < NBLK_N) ? blksum[t] : 0;
    sh[t] = v;
    __syncthreads();
    for (int off = 1; off < 256; off <<= 1) {
        int add = (t >= off) ? sh[t - off] : 0;
        __syncthreads();
        sh[t] += add;
        __syncthreads();
    }
    int excl = sh[t] - v;
    __syncthreads();
    sh[t] = excl;               // sh[b] = exclusive prefix of block b
    __syncthreads();
    int i = blockIdx.x * 256 + t;
    if (i < n) {
        int r = row_ptr[i] + sh[blockIdx.x];
        row_ptr[i] = r;
        cursor[i] = r;
    }
    if (i == 0) row_ptr[n] = nE;
}

// ---------------- fc_init: h0 = relu(features @ fc_w + fc_b) ----------------

#define FT_PITCH 132
#define FCNT 64

__global__ __launch_bounds__(256) void fc_init_kernel(
        const float* __restrict__ feat, const float* __restrict__ W,
        const float* __restrict__ bias, float* __restrict__ h, int n) {
    __shared__ float Wl[IN_DIM * HID];      // 32 KB
    __shared__ float ft[FCNT * FT_PITCH];   // 33 KB

    int base = blockIdx.x * FCNT;
    for (int i = threadIdx.x; i < IN_DIM * HID / 4; i += 256)
        *reinterpret_cast<v4f*>(&Wl[i * 4]) = *reinterpret_cast<const v4f*>(&W[i * 4]);
    {
        int f4 = threadIdx.x & 31;
        int r0 = threadIdx.x >> 5;
        for (int p = 0; p < 8; ++p) {
            int r = p * 8 + r0;
            int node = base + r;
            v4f v = {0.f, 0.f, 0.f, 0.f};
            if (node < n)
                v = __builtin_nontemporal_load(
                        reinterpret_cast<const v4f*>(&feat[(size_t)node * IN_DIM + f4 * 4]));
            *reinterpret_cast<v4f*>(&ft[r * FT_PITCH + f4 * 4]) = v;
        }
    }
    __syncthreads();

    int tx = threadIdx.x & 15;
    int ty = threadIdx.x >> 4;
    v4f acc[4];
    v4f b4 = *reinterpret_cast<const v4f*>(&bias[tx * 4]);
    acc[0] = b4; acc[1] = b4; acc[2] = b4; acc[3] = b4;

#pragma unroll 16
    for (int k = 0; k < IN_DIM; ++k) {
        v4f w4 = *reinterpret_cast<const v4f*>(&Wl[k * HID + tx * 4]);
        float a0 = ft[(ty * 4 + 0) * FT_PITCH + k];
        float a1 = ft[(ty * 4 + 1) * FT_PITCH + k];
        float a2 = ft[(ty * 4 + 2) * FT_PITCH + k];
        float a3 = ft[(ty * 4 + 3) * FT_PITCH + k];
        acc[0] += a0 * w4;
        acc[1] += a1 * w4;
        acc[2] += a2 * w4;
        acc[3] += a3 * w4;
    }
#pragma unroll
    for (int i = 0; i < 4; ++i) {
        int node = base + ty * 4 + i;
        if (node < n) {
            v4f o;
            o[0] = fmaxf(acc[i][0], 0.f);
            o[1] = fmaxf(acc[i][1], 0.f);
            o[2] = fmaxf(acc[i][2], 0.f);
            o[3] = fmaxf(acc[i][3], 0.f);
            *reinterpret_cast<v4f*>(&h[(size_t)node * HID + tx * 4]) = o;
        }
    }
}

// ---------------- fused GIN layer (512 threads, NT=64) ----------------
// Phase A: 8 waves x 8 nodes; 4 edges per load instruction (lane group g
// owns edge j*4+g, feature quad (lane&15)*4). Tail lanes carry index n
// (zero row) so the __shfl is unconditional -> convergent. col is read
// non-temporally (read-once) to keep L2 for the h rows.
// Phase B: 64x64x64 GEMM, 2 nodes x 4 outputs per thread, W in LDS.

__global__ __launch_bounds__(512) void gin_layer_kernel(
        const float* __restrict__ h_in, const int* __restrict__ row_ptr,
        const int* __restrict__ col, const float* __restrict__ W,
        const float* __restrict__ bias, const float* __restrict__ eps_arr, int layer,
        float* __restrict__ h_out, int n) {
    __shared__ float Wl[HID * HID];         // 16 KB
    __shared__ float rst[NT * RST_PITCH];   // 17 KB

    for (int i = threadIdx.x; i < HID * HID / 4; i += 512)
        *reinterpret_cast<v4f*>(&Wl[i * 4]) = *reinterpret_cast<const v4f*>(&W[i * 4]);

    int wid = threadIdx.x >> 6, lane = threadIdx.x & 63;
    int g = lane >> 4;          // edge subgroup 0..3
    int fo = (lane & 15) * 4;   // feature quad offset
    int base = blockIdx.x * NT;
    float eps1 = 1.f + eps_arr[layer];

    // phase A: gather-mean, 8 nodes per wave
    for (int t = 0; t < 8; ++t) {
        int r = wid * 8 + t;
        int node = base + r;
        if (node < n) {
            int s0 = row_ptr[node], s1 = row_ptr[node + 1];
            v4f acc = {0.f, 0.f, 0.f, 0.f};
            for (int e0 = s0; e0 < s1; e0 += 64) {
                int cnt = s1 - e0; if (cnt > 64) cnt = 64;
                int myc = (lane < cnt) ? __builtin_nontemporal_load(&col[e0 + lane]) : n;
                int jmax = (cnt + 3) >> 2;
#pragma unroll 4
                for (int j = 0; j < jmax; ++j) {
                    int idx = j * 4 + g;                      // <= 63 always
                    int sn = __shfl(myc, idx);                // convergent
                    acc += *reinterpret_cast<const v4f*>(&h_in[(size_t)sn * HID + fo]);
                }
            }
#pragma unroll
            for (int c = 0; c < 4; ++c) acc[c] += __shfl_xor(acc[c], 16);
#pragma unroll
            for (int c = 0; c < 4; ++c) acc[c] += __shfl_xor(acc[c], 32);
            int d = s1 - s0;
            float sc = (d > 0) ? 1.f / (float)d : 0.f;
            if (lane < 16) {
                v4f self = *reinterpret_cast<const v4f*>(&h_in[(size_t)node * HID + fo]);
                v4f rv = eps1 * self + acc * sc;
                *reinterpret_cast<v4f*>(&rst[r * RST_PITCH + fo]) = rv;
            }
        }
    }
    __syncthreads();

    // phase B: out = relu(rst @ W + b)
    int tx = threadIdx.x & 15;   // output quad
    int ty = threadIdx.x >> 4;   // node pair 0..31
    v4f b4 = *reinterpret_cast<const v4f*>(&bias[tx * 4]);
    v4f acc0 = b4, acc1 = b4;

#pragma unroll 16
    for (int k = 0; k < HID; ++k) {
        v4f w4 = *reinterpret_cast<const v4f*>(&Wl[k * HID + tx * 4]);
        float a0 = rst[(ty * 2 + 0) * RST_PITCH + k];
        float a1 = rst[(ty * 2 + 1) * RST_PITCH + k];
        acc0 += a0 * w4;
        acc1 += a1 * w4;
    }
    {
        int node = base + ty * 2;
        if (node < n) {
            v4f o;
            o[0] = fmaxf(acc0[0], 0.f); o[1] = fmaxf(acc0[1], 0.f);
            o[2] = fmaxf(acc0[2], 0.f); o[3] = fmaxf(acc0[3], 0.f);
            *reinterpret_cast<v4f*>(&h_out[(size_t)node * HID + tx * 4]) = o;
        }
        node = base + ty * 2 + 1;
        if (node < n) {
            v4f o;
            o[0] = fmaxf(acc1[0], 0.f); o[1] = fmaxf(acc1[1], 0.f);
            o[2] = fmaxf(acc1[2], 0.f); o[3] = fmaxf(acc1[3], 0.f);
            *reinterpret_cast<v4f*>(&h_out[(size_t)node * HID + tx * 4]) = o;
        }
    }
}

// ---------------- launch ----------------

extern "C" void kernel_launch(void* const* d_in, const int* in_sizes, int n_in,
                              void* d_out, int out_size, void* d_ws, size_t ws_size,
                              hipStream_t stream) {
    const float* feat = (const float*)d_in[0];
    const int*   src  = (const int*)d_in[1];
    const int*   dst  = (const int*)d_in[2];
    const float* fc_w = (const float*)d_in[3];
    const float* fc_b = (const float*)d_in[4];
    const float* w0   = (const float*)d_in[5];
    const float* b0   = (const float*)d_in[6];
    const float* w1   = (const float*)d_in[7];
    const float* b1   = (const float*)d_in[8];
    const float* w2   = (const float*)d_in[9];
    const float* b2   = (const float*)d_in[10];
    const float* eps  = (const float*)d_in[11];
    float* out = (float*)d_out;

    char* ws = (char*)d_ws;
    size_t off = 0;
    auto alloc = [&](size_t bytes) {
        size_t o = off;
        off += (bytes + 255) & ~(size_t)255;
        return (void*)(ws + o);
    };
    int*   deg     = (int*)alloc((size_t)N_NODES * 4);
    int*   row_ptr = (int*)alloc((size_t)(N_NODES + 1) * 4);
    int*   cursor  = (int*)alloc((size_t)N_NODES * 4);
    int*   blksum  = (int*)alloc(256 * 4);
    int*   col     = (int*)alloc((size_t)N_EDGES * 4);
    float* hA      = (float*)alloc((size_t)(N_NODES + 1) * HID * 4);
    float* hB      = (float*)alloc((size_t)(N_NODES + 1) * HID * 4);

    const int sweepBlocks = NXCD * 256;        // 2048: 8 ranges x 256 chunks

    zero_kernel<<<NBLK_N, 256, 0, stream>>>(deg, hA, hB);
    deg_sweep_kernel<<<sweepBlocks, 256, 0, stream>>>(dst, deg);
    scan1_kernel<<<NBLK_N, 256, 0, stream>>>(deg, row_ptr, blksum, N_NODES);
    scan23_kernel<<<NBLK_N, 256, 0, stream>>>(row_ptr, blksum, cursor, N_NODES, N_EDGES);
    fill_sweep_kernel<<<sweepBlocks, 256, 0, stream>>>(src, dst, cursor, col);

    const int fcBlocks = (N_NODES + FCNT - 1) / FCNT;   // 782
    fc_init_kernel<<<fcBlocks, 256, 0, stream>>>(feat, fc_w, fc_b, hA, N_NODES);
    const int ginBlocks = (N_NODES + NT - 1) / NT;      // 782
    gin_layer_kernel<<<ginBlocks, 512, 0, stream>>>(hA, row_ptr, col, w0, b0, eps, 0, hB, N_NODES);
    gin_layer_kernel<<<ginBlocks, 512, 0, stream>>>(hB, row_ptr, col, w1, b1, eps, 1, hA, N_NODES);
    gin_layer_kernel<<<ginBlocks, 512, 0, stream>>>(hA, row_ptr, col, w2, b2, eps, 2, out, N_NODES);
}

// Round 8
// 180.714 us; speedup vs baseline: 1.3192x; 1.3192x over previous
//
#include <hip/hip_runtime.h>

#define N_NODES 50000
#define N_EDGES 800000
#define IN_DIM 128
#define HID 64
#define NT 64        // nodes per block in gin layer
#define RST_PITCH 68 // 272B rows: 16B-aligned, conflict-free broadcasts
#define NXCD 8
#define RANGE (N_NODES / NXCD)             // 6250 nodes per range (25KB LDS)
#define NCHUNK 32
#define EDGES_PER_CHUNK (N_EDGES / NCHUNK) // 25000
#define I4_PER_CHUNK (EDGES_PER_CHUNK / 4) // 6250
#define NBLK_N 196                         // ceil(N_NODES/256)

using v4f = __attribute__((ext_vector_type(4))) float;
using v4i = __attribute__((ext_vector_type(4))) int;

// ---------------- CSR build: atomic-free (LDS histograms) ----------------
// 8 node-ranges x 32 edge-chunks. blockIdx = c*8 + r, so blockIdx%8 == r:
// all 32 blocks of range r land on XCD r (round-robin heuristic), keeping
// that range's col segment resident in one L2 during place_kernel.

__global__ __launch_bounds__(256) void hist_kernel(
        const int* __restrict__ dst, int* __restrict__ H) {
    __shared__ int cnt[RANGE];
    int r = blockIdx.x & (NXCD - 1), c = blockIdx.x >> 3;
    int lo = r * RANGE;
    for (int i = threadIdx.x; i < RANGE; i += 256) cnt[i] = 0;
    __syncthreads();
    const v4i* d4p = reinterpret_cast<const v4i*>(dst) + c * I4_PER_CHUNK;
#pragma unroll 2
    for (int i = threadIdx.x; i < I4_PER_CHUNK; i += 256) {
        v4i d4 = d4p[i];
        int a;
        a = d4.x - lo; if ((unsigned)a < RANGE) atomicAdd(&cnt[a], 1);
        a = d4.y - lo; if ((unsigned)a < RANGE) atomicAdd(&cnt[a], 1);
        a = d4.z - lo; if ((unsigned)a < RANGE) atomicAdd(&cnt[a], 1);
        a = d4.w - lo; if ((unsigned)a < RANGE) atomicAdd(&cnt[a], 1);
    }
    __syncthreads();
    int* Hrow = H + (size_t)c * N_NODES + lo;
    for (int i = threadIdx.x; i < RANGE; i += 256) Hrow[i] = cnt[i];
}

// deg = sum over chunks of H; per-block inclusive scan -> row_ptr (block-local
// exclusive) + blksum. Also zeroes row n of hA/hB (gather pad target).
__global__ void scanA_kernel(const int* __restrict__ H, int* __restrict__ row_ptr,
                             int* __restrict__ blksum,
                             float* __restrict__ hA, float* __restrict__ hB) {
    __shared__ int sh[256];
    int t = threadIdx.x;
    int node = blockIdx.x * 256 + t;
    int d = 0;
    if (node < N_NODES)
#pragma unroll 8
        for (int c = 0; c < NCHUNK; ++c) d += H[(size_t)c * N_NODES + node];
    sh[t] = d;
    __syncthreads();
    for (int off = 1; off < 256; off <<= 1) {
        int add = (t >= off) ? sh[t - off] : 0;
        __syncthreads();
        sh[t] += add;
        __syncthreads();
    }
    int incl = sh[t];
    if (node < N_NODES) row_ptr[node] = incl - d;
    if (t == 255) blksum[blockIdx.x] = incl;
    if (blockIdx.x == 0 && t < HID) {
        hA[(size_t)N_NODES * HID + t] = 0.f;
        hB[(size_t)N_NODES * HID + t] = 0.f;
    }
}

// scan block sums (redundantly per block), finalize row_ptr, and emit
// per-(chunk,node) placement offsets P[c][node] = row_ptr + prefix_c(H).
__global__ void scanB_kernel(const int* __restrict__ H, int* __restrict__ row_ptr,
                             int* __restrict__ P, const int* __restrict__ blksum) {
    __shared__ int sh[256];
    int t = threadIdx.x;
    int v = (t < NBLK_N) ? blksum[t] : 0;
    sh[t] = v;
    __syncthreads();
    for (int off = 1; off < 256; off <<= 1) {
        int add = (t >= off) ? sh[t - off] : 0;
        __syncthreads();
        sh[t] += add;
        __syncthreads();
    }
    int excl = sh[t] - v;
    __syncthreads();
    sh[t] = excl;
    __syncthreads();
    int node = blockIdx.x * 256 + t;
    if (node < N_NODES) {
        int run = row_ptr[node] + sh[blockIdx.x];
        row_ptr[node] = run;
#pragma unroll 8
        for (int c = 0; c < NCHUNK; ++c) {
            P[(size_t)c * N_NODES + node] = run;
            run += H[(size_t)c * N_NODES + node];
        }
    }
    if (node == 0) row_ptr[N_NODES] = N_EDGES;
}

// place edges: LDS cursors (no global atomics; LDS atomic bump is ~20cy).
__global__ __launch_bounds__(256) void place_kernel(
        const int* __restrict__ src, const int* __restrict__ dst,
        const int* __restrict__ P, int* __restrict__ col) {
    __shared__ int cur[RANGE];
    int r = blockIdx.x & (NXCD - 1), c = blockIdx.x >> 3;
    int lo = r * RANGE;
    const int* Pc = P + (size_t)c * N_NODES + lo;
    for (int i = threadIdx.x; i < RANGE; i += 256) cur[i] = Pc[i];
    __syncthreads();
    const v4i* d4p = reinterpret_cast<const v4i*>(dst) + c * I4_PER_CHUNK;
    const v4i* s4p = reinterpret_cast<const v4i*>(src) + c * I4_PER_CHUNK;
#pragma unroll 2
    for (int i = threadIdx.x; i < I4_PER_CHUNK; i += 256) {
        v4i d4 = d4p[i];
        v4i s4 = s4p[i];
        int a;
        a = d4.x - lo; if ((unsigned)a < RANGE) col[atomicAdd(&cur[a], 1)] = s4.x;
        a = d4.y - lo; if ((unsigned)a < RANGE) col[atomicAdd(&cur[a], 1)] = s4.y;
        a = d4.z - lo; if ((unsigned)a < RANGE) col[atomicAdd(&cur[a], 1)] = s4.z;
        a = d4.w - lo; if ((unsigned)a < RANGE) col[atomicAdd(&cur[a], 1)] = s4.w;
    }
}

// ---------------- fc_init: h0 = relu(features @ fc_w + fc_b) ----------------

#define FT_PITCH 132
#define FCNT 64

__global__ __launch_bounds__(256) void fc_init_kernel(
        const float* __restrict__ feat, const float* __restrict__ W,
        const float* __restrict__ bias, float* __restrict__ h, int n) {
    __shared__ float Wl[IN_DIM * HID];      // 32 KB
    __shared__ float ft[FCNT * FT_PITCH];   // 33 KB

    int base = blockIdx.x * FCNT;
    for (int i = threadIdx.x; i < IN_DIM * HID / 4; i += 256)
        *reinterpret_cast<v4f*>(&Wl[i * 4]) = *reinterpret_cast<const v4f*>(&W[i * 4]);
    {
        int f4 = threadIdx.x & 31;
        int r0 = threadIdx.x >> 5;
        for (int p = 0; p < 8; ++p) {
            int r = p * 8 + r0;
            int node = base + r;
            v4f v = {0.f, 0.f, 0.f, 0.f};
            if (node < n)
                v = *reinterpret_cast<const v4f*>(&feat[(size_t)node * IN_DIM + f4 * 4]);
            *reinterpret_cast<v4f*>(&ft[r * FT_PITCH + f4 * 4]) = v;
        }
    }
    __syncthreads();

    int tx = threadIdx.x & 15;
    int ty = threadIdx.x >> 4;
    v4f acc[4];
    v4f b4 = *reinterpret_cast<const v4f*>(&bias[tx * 4]);
    acc[0] = b4; acc[1] = b4; acc[2] = b4; acc[3] = b4;

#pragma unroll 16
    for (int k = 0; k < IN_DIM; ++k) {
        v4f w4 = *reinterpret_cast<const v4f*>(&Wl[k * HID + tx * 4]);
        float a0 = ft[(ty * 4 + 0) * FT_PITCH + k];
        float a1 = ft[(ty * 4 + 1) * FT_PITCH + k];
        float a2 = ft[(ty * 4 + 2) * FT_PITCH + k];
        float a3 = ft[(ty * 4 + 3) * FT_PITCH + k];
        acc[0] += a0 * w4;
        acc[1] += a1 * w4;
        acc[2] += a2 * w4;
        acc[3] += a3 * w4;
    }
#pragma unroll
    for (int i = 0; i < 4; ++i) {
        int node = base + ty * 4 + i;
        if (node < n) {
            v4f o;
            o[0] = fmaxf(acc[i][0], 0.f);
            o[1] = fmaxf(acc[i][1], 0.f);
            o[2] = fmaxf(acc[i][2], 0.f);
            o[3] = fmaxf(acc[i][3], 0.f);
            *reinterpret_cast<v4f*>(&h[(size_t)node * HID + tx * 4]) = o;
        }
    }
}

// ---------------- fused GIN layer (512 threads, NT=64) ----------------
// Phase A: 8 waves x 8 nodes; 4 edges per load instruction (lane group g
// owns edge j*4+g, feature quad (lane&15)*4). Tail lanes carry index n
// (zero row) so the __shfl is unconditional -> convergent.
// Phase B: 64x64x64 GEMM, 2 nodes x 4 outputs per thread, W in LDS.

__global__ __launch_bounds__(512) void gin_layer_kernel(
        const float* __restrict__ h_in, const int* __restrict__ row_ptr,
        const int* __restrict__ col, const float* __restrict__ W,
        const float* __restrict__ bias, const float* __restrict__ eps_arr, int layer,
        float* __restrict__ h_out, int n) {
    __shared__ float Wl[HID * HID];         // 16 KB
    __shared__ float rst[NT * RST_PITCH];   // 17 KB

    for (int i = threadIdx.x; i < HID * HID / 4; i += 512)
        *reinterpret_cast<v4f*>(&Wl[i * 4]) = *reinterpret_cast<const v4f*>(&W[i * 4]);

    int wid = threadIdx.x >> 6, lane = threadIdx.x & 63;
    int g = lane >> 4;          // edge subgroup 0..3
    int fo = (lane & 15) * 4;   // feature quad offset
    int base = blockIdx.x * NT;
    float eps1 = 1.f + eps_arr[layer];

    // phase A: gather-mean, 8 nodes per wave
    for (int t = 0; t < 8; ++t) {
        int r = wid * 8 + t;
        int node = base + r;
        if (node < n) {
            int s0 = row_ptr[node], s1 = row_ptr[node + 1];
            v4f acc = {0.f, 0.f, 0.f, 0.f};
            for (int e0 = s0; e0 < s1; e0 += 64) {
                int cnt = s1 - e0; if (cnt > 64) cnt = 64;
                int myc = (lane < cnt) ? col[e0 + lane] : n;  // tail -> zero row
                int jmax = (cnt + 3) >> 2;
#pragma unroll 4
                for (int j = 0; j < jmax; ++j) {
                    int idx = j * 4 + g;                      // <= 63 always
                    int sn = __shfl(myc, idx);                // convergent
                    acc += *reinterpret_cast<const v4f*>(&h_in[(size_t)sn * HID + fo]);
                }
            }
#pragma unroll
            for (int c = 0; c < 4; ++c) acc[c] += __shfl_xor(acc[c], 16);
#pragma unroll
            for (int c = 0; c < 4; ++c) acc[c] += __shfl_xor(acc[c], 32);
            int d = s1 - s0;
            float sc = (d > 0) ? 1.f / (float)d : 0.f;
            if (lane < 16) {
                v4f self = *reinterpret_cast<const v4f*>(&h_in[(size_t)node * HID + fo]);
                v4f rv = eps1 * self + acc * sc;
                *reinterpret_cast<v4f*>(&rst[r * RST_PITCH + fo]) = rv;
            }
        }
    }
    __syncthreads();

    // phase B: out = relu(rst @ W + b)
    int tx = threadIdx.x & 15;   // output quad
    int ty = threadIdx.x >> 4;   // node pair 0..31
    v4f b4 = *reinterpret_cast<const v4f*>(&bias[tx * 4]);
    v4f acc0 = b4, acc1 = b4;

#pragma unroll 16
    for (int k = 0; k < HID; ++k) {
        v4f w4 = *reinterpret_cast<const v4f*>(&Wl[k * HID + tx * 4]);
        float a0 = rst[(ty * 2 + 0) * RST_PITCH + k];
        float a1 = rst[(ty * 2 + 1) * RST_PITCH + k];
        acc0 += a0 * w4;
        acc1 += a1 * w4;
    }
    {
        int node = base + ty * 2;
        if (node < n) {
            v4f o;
            o[0] = fmaxf(acc0[0], 0.f); o[1] = fmaxf(acc0[1], 0.f);
            o[2] = fmaxf(acc0[2], 0.f); o[3] = fmaxf(acc0[3], 0.f);
            *reinterpret_cast<v4f*>(&h_out[(size_t)node * HID + tx * 4]) = o;
        }
        node = base + ty * 2 + 1;
        if (node < n) {
            v4f o;
            o[0] = fmaxf(acc1[0], 0.f); o[1] = fmaxf(acc1[1], 0.f);
            o[2] = fmaxf(acc1[2], 0.f); o[3] = fmaxf(acc1[3], 0.f);
            *reinterpret_cast<v4f*>(&h_out[(size_t)node * HID + tx * 4]) = o;
        }
    }
}

// ---------------- launch ----------------

extern "C" void kernel_launch(void* const* d_in, const int* in_sizes, int n_in,
                              void* d_out, int out_size, void* d_ws, size_t ws_size,
                              hipStream_t stream) {
    const float* feat = (const float*)d_in[0];
    const int*   src  = (const int*)d_in[1];
    const int*   dst  = (const int*)d_in[2];
    const float* fc_w = (const float*)d_in[3];
    const float* fc_b = (const float*)d_in[4];
    const float* w0   = (const float*)d_in[5];
    const float* b0   = (const float*)d_in[6];
    const float* w1   = (const float*)d_in[7];
    const float* b1   = (const float*)d_in[8];
    const float* w2   = (const float*)d_in[9];
    const float* b2   = (const float*)d_in[10];
    const float* eps  = (const float*)d_in[11];
    float* out = (float*)d_out;

    char* ws = (char*)d_ws;
    size_t off = 0;
    auto alloc = [&](size_t bytes) {
        size_t o = off;
        off += (bytes + 255) & ~(size_t)255;
        return (void*)(ws + o);
    };
    int*   row_ptr = (int*)alloc((size_t)(N_NODES + 1) * 4);
    int*   blksum  = (int*)alloc(256 * 4);
    int*   H       = (int*)alloc((size_t)NCHUNK * N_NODES * 4);  // 6.4 MB
    int*   P       = (int*)alloc((size_t)NCHUNK * N_NODES * 4);  // 6.4 MB
    int*   col     = (int*)alloc((size_t)N_EDGES * 4);
    float* hA      = (float*)alloc((size_t)(N_NODES + 1) * HID * 4);
    float* hB      = (float*)alloc((size_t)(N_NODES + 1) * HID * 4);

    const int csrBlocks = NXCD * NCHUNK;   // 256: 1 block/CU

    hist_kernel<<<csrBlocks, 256, 0, stream>>>(dst, H);
    scanA_kernel<<<NBLK_N, 256, 0, stream>>>(H, row_ptr, blksum, hA, hB);
    scanB_kernel<<<NBLK_N, 256, 0, stream>>>(H, row_ptr, P, blksum);
    place_kernel<<<csrBlocks, 256, 0, stream>>>(src, dst, P, col);

    const int fcBlocks = (N_NODES + FCNT - 1) / FCNT;   // 782
    fc_init_kernel<<<fcBlocks, 256, 0, stream>>>(feat, fc_w, fc_b, hA, N_NODES);
    const int ginBlocks = (N_NODES + NT - 1) / NT;      // 782
    gin_layer_kernel<<<ginBlocks, 512, 0, stream>>>(hA, row_ptr, col, w0, b0, eps, 0, hB, N_NODES);
    gin_layer_kernel<<<ginBlocks, 512, 0, stream>>>(hB, row_ptr, col, w1, b1, eps, 1, hA, N_NODES);
    gin_layer_kernel<<<ginBlocks, 512, 0, stream>>>(hA, row_ptr, col, w2, b2, eps, 2, out, N_NODES);
}

// Round 9
// 176.318 us; speedup vs baseline: 1.3521x; 1.0249x over previous
//
#include <hip/hip_runtime.h>

#define N_NODES 50000
#define N_EDGES 800000
#define IN_DIM 128
#define HID 64
#define NT 32        // nodes per block in gin layer
#define RST_PITCH 68 // 272B rows: 16B-aligned, conflict-free broadcasts
#define NXCD 8
#define RANGE (N_NODES / NXCD)             // 6250 nodes per range (25KB LDS)
#define NCHUNK 32
#define EDGES_PER_CHUNK (N_EDGES / NCHUNK) // 25000
#define I4_PER_CHUNK (EDGES_PER_CHUNK / 4) // 6250
#define NBLK_N 196                         // ceil(N_NODES/256)

using v4f = __attribute__((ext_vector_type(4))) float;
using v4i = __attribute__((ext_vector_type(4))) int;

// ---------------- CSR build: atomic-free (LDS histograms) ----------------
// 8 node-ranges x 32 edge-chunks. blockIdx = c*8 + r, so blockIdx%8 == r:
// all 32 blocks of range r land on XCD r (round-robin heuristic), keeping
// that range's col segment resident in one L2 during place_kernel.

__global__ __launch_bounds__(256) void hist_kernel(
        const int* __restrict__ dst, int* __restrict__ H) {
    __shared__ int cnt[RANGE];
    int r = blockIdx.x & (NXCD - 1), c = blockIdx.x >> 3;
    int lo = r * RANGE;
    for (int i = threadIdx.x; i < RANGE; i += 256) cnt[i] = 0;
    __syncthreads();
    const v4i* d4p = reinterpret_cast<const v4i*>(dst) + c * I4_PER_CHUNK;
#pragma unroll 2
    for (int i = threadIdx.x; i < I4_PER_CHUNK; i += 256) {
        v4i d4 = d4p[i];
        int a;
        a = d4.x - lo; if ((unsigned)a < RANGE) atomicAdd(&cnt[a], 1);
        a = d4.y - lo; if ((unsigned)a < RANGE) atomicAdd(&cnt[a], 1);
        a = d4.z - lo; if ((unsigned)a < RANGE) atomicAdd(&cnt[a], 1);
        a = d4.w - lo; if ((unsigned)a < RANGE) atomicAdd(&cnt[a], 1);
    }
    __syncthreads();
    int* Hrow = H + (size_t)c * N_NODES + lo;
    for (int i = threadIdx.x; i < RANGE; i += 256) Hrow[i] = cnt[i];
}

// deg = sum over chunks of H; per-block inclusive scan -> row_ptr (block-local
// exclusive) + blksum. Also zeroes row n of hA/hB (gather pad target).
__global__ void scanA_kernel(const int* __restrict__ H, int* __restrict__ row_ptr,
                             int* __restrict__ blksum,
                             float* __restrict__ hA, float* __restrict__ hB) {
    __shared__ int sh[256];
    int t = threadIdx.x;
    int node = blockIdx.x * 256 + t;
    int d = 0;
    if (node < N_NODES)
#pragma unroll 8
        for (int c = 0; c < NCHUNK; ++c) d += H[(size_t)c * N_NODES + node];
    sh[t] = d;
    __syncthreads();
    for (int off = 1; off < 256; off <<= 1) {
        int add = (t >= off) ? sh[t - off] : 0;
        __syncthreads();
        sh[t] += add;
        __syncthreads();
    }
    int incl = sh[t];
    if (node < N_NODES) row_ptr[node] = incl - d;
    if (t == 255) blksum[blockIdx.x] = incl;
    if (blockIdx.x == 0 && t < HID) {
        hA[(size_t)N_NODES * HID + t] = 0.f;
        hB[(size_t)N_NODES * HID + t] = 0.f;
    }
}

// scan block sums (redundantly per block), finalize row_ptr, and emit
// per-(chunk,node) placement offsets P[c][node] = row_ptr + prefix_c(H).
__global__ void scanB_kernel(const int* __restrict__ H, int* __restrict__ row_ptr,
                             int* __restrict__ P, const int* __restrict__ blksum) {
    __shared__ int sh[256];
    int t = threadIdx.x;
    int v = (t < NBLK_N) ? blksum[t] : 0;
    sh[t] = v;
    __syncthreads();
    for (int off = 1; off < 256; off <<= 1) {
        int add = (t >= off) ? sh[t - off] : 0;
        __syncthreads();
        sh[t] += add;
        __syncthreads();
    }
    int excl = sh[t] - v;
    __syncthreads();
    sh[t] = excl;
    __syncthreads();
    int node = blockIdx.x * 256 + t;
    if (node < N_NODES) {
        int run = row_ptr[node] + sh[blockIdx.x];
        row_ptr[node] = run;
#pragma unroll 8
        for (int c = 0; c < NCHUNK; ++c) {
            P[(size_t)c * N_NODES + node] = run;
            run += H[(size_t)c * N_NODES + node];
        }
    }
    if (node == 0) row_ptr[N_NODES] = N_EDGES;
}

// place edges: LDS cursors (no global atomics; LDS atomic bump is cheap).
__global__ __launch_bounds__(256) void place_kernel(
        const int* __restrict__ src, const int* __restrict__ dst,
        const int* __restrict__ P, int* __restrict__ col) {
    __shared__ int cur[RANGE];
    int r = blockIdx.x & (NXCD - 1), c = blockIdx.x >> 3;
    int lo = r * RANGE;
    const int* Pc = P + (size_t)c * N_NODES + lo;
    for (int i = threadIdx.x; i < RANGE; i += 256) cur[i] = Pc[i];
    __syncthreads();
    const v4i* d4p = reinterpret_cast<const v4i*>(dst) + c * I4_PER_CHUNK;
    const v4i* s4p = reinterpret_cast<const v4i*>(src) + c * I4_PER_CHUNK;
#pragma unroll 2
    for (int i = threadIdx.x; i < I4_PER_CHUNK; i += 256) {
        v4i d4 = d4p[i];
        v4i s4 = s4p[i];
        int a;
        a = d4.x - lo; if ((unsigned)a < RANGE) col[atomicAdd(&cur[a], 1)] = s4.x;
        a = d4.y - lo; if ((unsigned)a < RANGE) col[atomicAdd(&cur[a], 1)] = s4.y;
        a = d4.z - lo; if ((unsigned)a < RANGE) col[atomicAdd(&cur[a], 1)] = s4.z;
        a = d4.w - lo; if ((unsigned)a < RANGE) col[atomicAdd(&cur[a], 1)] = s4.w;
    }
}

// ---------------- fc_init: h0 = relu(features @ fc_w + fc_b) ----------------

#define FT_PITCH 132
#define FCNT 64

__global__ __launch_bounds__(256) void fc_init_kernel(
        const float* __restrict__ feat, const float* __restrict__ W,
        const float* __restrict__ bias, float* __restrict__ h, int n) {
    __shared__ float Wl[IN_DIM * HID];      // 32 KB
    __shared__ float ft[FCNT * FT_PITCH];   // 33 KB

    int base = blockIdx.x * FCNT;
    for (int i = threadIdx.x; i < IN_DIM * HID / 4; i += 256)
        *reinterpret_cast<v4f*>(&Wl[i * 4]) = *reinterpret_cast<const v4f*>(&W[i * 4]);
    {
        int f4 = threadIdx.x & 31;
        int r0 = threadIdx.x >> 5;
        for (int p = 0; p < 8; ++p) {
            int r = p * 8 + r0;
            int node = base + r;
            v4f v = {0.f, 0.f, 0.f, 0.f};
            if (node < n)
                v = *reinterpret_cast<const v4f*>(&feat[(size_t)node * IN_DIM + f4 * 4]);
            *reinterpret_cast<v4f*>(&ft[r * FT_PITCH + f4 * 4]) = v;
        }
    }
    __syncthreads();

    int tx = threadIdx.x & 15;
    int ty = threadIdx.x >> 4;
    v4f acc[4];
    v4f b4 = *reinterpret_cast<const v4f*>(&bias[tx * 4]);
    acc[0] = b4; acc[1] = b4; acc[2] = b4; acc[3] = b4;

#pragma unroll 16
    for (int k = 0; k < IN_DIM; ++k) {
        v4f w4 = *reinterpret_cast<const v4f*>(&Wl[k * HID + tx * 4]);
        float a0 = ft[(ty * 4 + 0) * FT_PITCH + k];
        float a1 = ft[(ty * 4 + 1) * FT_PITCH + k];
        float a2 = ft[(ty * 4 + 2) * FT_PITCH + k];
        float a3 = ft[(ty * 4 + 3) * FT_PITCH + k];
        acc[0] += a0 * w4;
        acc[1] += a1 * w4;
        acc[2] += a2 * w4;
        acc[3] += a3 * w4;
    }
#pragma unroll
    for (int i = 0; i < 4; ++i) {
        int node = base + ty * 4 + i;
        if (node < n) {
            v4f o;
            o[0] = fmaxf(acc[i][0], 0.f);
            o[1] = fmaxf(acc[i][1], 0.f);
            o[2] = fmaxf(acc[i][2], 0.f);
            o[3] = fmaxf(acc[i][3], 0.f);
            *reinterpret_cast<v4f*>(&h[(size_t)node * HID + tx * 4]) = o;
        }
    }
}

// ---------------- fused GIN layer (512 threads, NT=32) ----------------
// Phase A: 8 waves x 4 nodes, processed as 2 PAIRS with fused j-loops
// (jmax = max of the pair): 8 independent 1KB gathers in flight per wave.
// Overshoot lanes/iters read zero row n (L1-hot) -- convergent, branch-free.
// LDS 24.7KB -> 4 blocks/CU = 32 waves/CU (occupancy cap); 1563 blocks.
// Phase B: 32x64x64 GEMM, 1 node x 4 outputs per thread, W in LDS.

__global__ __launch_bounds__(512) void gin_layer_kernel(
        const float* __restrict__ h_in, const int* __restrict__ row_ptr,
        const int* __restrict__ col, const float* __restrict__ W,
        const float* __restrict__ bias, const float* __restrict__ eps_arr, int layer,
        float* __restrict__ h_out, int n) {
    __shared__ float Wl[HID * HID];         // 16 KB
    __shared__ float rst[NT * RST_PITCH];   // 8.7 KB

    for (int i = threadIdx.x; i < HID * HID / 4; i += 512)
        *reinterpret_cast<v4f*>(&Wl[i * 4]) = *reinterpret_cast<const v4f*>(&W[i * 4]);

    int wid = threadIdx.x >> 6, lane = threadIdx.x & 63;
    int g = lane >> 4;          // edge subgroup 0..3
    int fo = (lane & 15) * 4;   // feature quad offset
    int base = blockIdx.x * NT;
    int n0 = base + wid * 4;    // this wave's 4 nodes
    float eps1 = 1.f + eps_arr[layer];

#pragma unroll
    for (int p = 0; p < 2; ++p) {
        int na = n0 + p * 2, nb = na + 1;
        bool va = na < n, vb = nb < n;
        int s0a = 0, s1a = 0, s0b = 0, s1b = 0;
        if (va) { s0a = row_ptr[na]; s1a = row_ptr[na + 1]; }
        if (vb) { s0b = row_ptr[nb]; s1b = row_ptr[nb + 1]; }
        int da = s1a - s0a, db = s1b - s0b;
        int ca = da > 64 ? 64 : da;
        int cb = db > 64 ? 64 : db;
        int myca = (va && lane < ca) ? col[s0a + lane] : n;   // pad -> zero row
        int mycb = (vb && lane < cb) ? col[s0b + lane] : n;
        v4f acca = {0.f, 0.f, 0.f, 0.f}, accb = {0.f, 0.f, 0.f, 0.f};
        int jma = (ca + 3) >> 2, jmb = (cb + 3) >> 2;
        int jm = jma > jmb ? jma : jmb;
        for (int j = 0; j < jm; ++j) {
            int idx = j * 4 + g;
            int sa = __shfl(myca, idx);                       // convergent
            int sb = __shfl(mycb, idx);
            acca += *reinterpret_cast<const v4f*>(&h_in[(size_t)sa * HID + fo]);
            accb += *reinterpret_cast<const v4f*>(&h_in[(size_t)sb * HID + fo]);
        }
        // remainder chunks (degree > 64) — rare, per node
        for (int e0 = s0a + 64; e0 < s1a; e0 += 64) {
            int c = s1a - e0; if (c > 64) c = 64;
            int m = (lane < c) ? col[e0 + lane] : n;
            int jmr = (c + 3) >> 2;
            for (int j = 0; j < jmr; ++j) {
                int sn = __shfl(m, j * 4 + g);
                acca += *reinterpret_cast<const v4f*>(&h_in[(size_t)sn * HID + fo]);
            }
        }
        for (int e0 = s0b + 64; e0 < s1b; e0 += 64) {
            int c = s1b - e0; if (c > 64) c = 64;
            int m = (lane < c) ? col[e0 + lane] : n;
            int jmr = (c + 3) >> 2;
            for (int j = 0; j < jmr; ++j) {
                int sn = __shfl(m, j * 4 + g);
                accb += *reinterpret_cast<const v4f*>(&h_in[(size_t)sn * HID + fo]);
            }
        }
#pragma unroll
        for (int c = 0; c < 4; ++c) {
            acca[c] += __shfl_xor(acca[c], 16);
            acca[c] += __shfl_xor(acca[c], 32);
            accb[c] += __shfl_xor(accb[c], 16);
            accb[c] += __shfl_xor(accb[c], 32);
        }
        if (va && lane < 16) {
            float sc = (da > 0) ? 1.f / (float)da : 0.f;
            v4f self = *reinterpret_cast<const v4f*>(&h_in[(size_t)na * HID + fo]);
            v4f rv = eps1 * self + acca * sc;
            *reinterpret_cast<v4f*>(&rst[(wid * 4 + p * 2) * RST_PITCH + fo]) = rv;
        }
        if (vb && lane < 16) {
            float sc = (db > 0) ? 1.f / (float)db : 0.f;
            v4f self = *reinterpret_cast<const v4f*>(&h_in[(size_t)nb * HID + fo]);
            v4f rv = eps1 * self + accb * sc;
            *reinterpret_cast<v4f*>(&rst[(wid * 4 + p * 2 + 1) * RST_PITCH + fo]) = rv;
        }
    }
    __syncthreads();

    // phase B: out = relu(rst @ W + b); 1 node x 4 outputs per thread
    int tx = threadIdx.x & 15;   // output quad
    int ty = threadIdx.x >> 4;   // node 0..31
    v4f a4 = *reinterpret_cast<const v4f*>(&bias[tx * 4]);
#pragma unroll 16
    for (int k = 0; k < HID; ++k) {
        v4f w4 = *reinterpret_cast<const v4f*>(&Wl[k * HID + tx * 4]);
        a4 += rst[ty * RST_PITCH + k] * w4;
    }
    int node = base + ty;
    if (node < n) {
        v4f o;
        o[0] = fmaxf(a4[0], 0.f); o[1] = fmaxf(a4[1], 0.f);
        o[2] = fmaxf(a4[2], 0.f); o[3] = fmaxf(a4[3], 0.f);
        *reinterpret_cast<v4f*>(&h_out[(size_t)node * HID + tx * 4]) = o;
    }
}

// ---------------- launch ----------------

extern "C" void kernel_launch(void* const* d_in, const int* in_sizes, int n_in,
                              void* d_out, int out_size, void* d_ws, size_t ws_size,
                              hipStream_t stream) {
    const float* feat = (const float*)d_in[0];
    const int*   src  = (const int*)d_in[1];
    const int*   dst  = (const int*)d_in[2];
    const float* fc_w = (const float*)d_in[3];
    const float* fc_b = (const float*)d_in[4];
    const float* w0   = (const float*)d_in[5];
    const float* b0   = (const float*)d_in[6];
    const float* w1   = (const float*)d_in[7];
    const float* b1   = (const float*)d_in[8];
    const float* w2   = (const float*)d_in[9];
    const float* b2   = (const float*)d_in[10];
    const float* eps  = (const float*)d_in[11];
    float* out = (float*)d_out;

    char* ws = (char*)d_ws;
    size_t off = 0;
    auto alloc = [&](size_t bytes) {
        size_t o = off;
        off += (bytes + 255) & ~(size_t)255;
        return (void*)(ws + o);
    };
    int*   row_ptr = (int*)alloc((size_t)(N_NODES + 1) * 4);
    int*   blksum  = (int*)alloc(256 * 4);
    int*   H       = (int*)alloc((size_t)NCHUNK * N_NODES * 4);  // 6.4 MB
    int*   P       = (int*)alloc((size_t)NCHUNK * N_NODES * 4);  // 6.4 MB
    int*   col     = (int*)alloc((size_t)N_EDGES * 4);
    float* hA      = (float*)alloc((size_t)(N_NODES + 1) * HID * 4);
    float* hB      = (float*)alloc((size_t)(N_NODES + 1) * HID * 4);

    const int csrBlocks = NXCD * NCHUNK;   // 256: 1 block/CU

    hist_kernel<<<csrBlocks, 256, 0, stream>>>(dst, H);
    scanA_kernel<<<NBLK_N, 256, 0, stream>>>(H, row_ptr, blksum, hA, hB);
    scanB_kernel<<<NBLK_N, 256, 0, stream>>>(H, row_ptr, P, blksum);
    place_kernel<<<csrBlocks, 256, 0, stream>>>(src, dst, P, col);

    const int fcBlocks = (N_NODES + FCNT - 1) / FCNT;   // 782
    fc_init_kernel<<<fcBlocks, 256, 0, stream>>>(feat, fc_w, fc_b, hA, N_NODES);
    const int ginBlocks = (N_NODES + NT - 1) / NT;      // 1563
    gin_layer_kernel<<<ginBlocks, 512, 0, stream>>>(hA, row_ptr, col, w0, b0, eps, 0, hB, N_NODES);
    gin_layer_kernel<<<ginBlocks, 512, 0, stream>>>(hB, row_ptr, col, w1, b1, eps, 1, hA, N_NODES);
    gin_layer_kernel<<<ginBlocks, 512, 0, stream>>>(hA, row_ptr, col, w2, b2, eps, 2, out, N_NODES);
}